// Round 12
// baseline (181.310 us; speedup 1.0000x reference)
//
#include <hip/hip_runtime.h>

typedef __attribute__((ext_vector_type(8))) short short8;
typedef __attribute__((ext_vector_type(4))) float floatx4;
typedef __attribute__((ext_vector_type(2))) unsigned uint2e;

static __device__ __forceinline__ unsigned short f2bf(float f) {
    unsigned u = __float_as_uint(f);
    u += 0x7FFFu + ((u >> 16) & 1u);
    return (unsigned short)(u >> 16);
}

// VALU butterfly reductions via gfx950 permlane-swap BUILTINS (no DS pipe).
// R10 lesson: hand-asm with tied "+v" operands let regalloc coalesce the
// two registers -> self-swap -> NaN. Builtin owns the 2-register contract.
static __device__ __forceinline__ float pl16_sum(float x) {
    unsigned u = __float_as_uint(x);
    uint2e p = __builtin_amdgcn_permlane16_swap(u, u, false, false);
    return __uint_as_float(p.x) + __uint_as_float(p.y);
}
static __device__ __forceinline__ float pl32_sum(float x) {
    unsigned u = __float_as_uint(x);
    uint2e p = __builtin_amdgcn_permlane32_swap(u, u, false, false);
    return __uint_as_float(p.x) + __uint_as_float(p.y);
}
static __device__ __forceinline__ int pl16_or(int x) {
    uint2e p = __builtin_amdgcn_permlane16_swap((unsigned)x, (unsigned)x, false, false);
    return (int)(p.x | p.y);
}
static __device__ __forceinline__ int pl32_or(int x) {
    uint2e p = __builtin_amdgcn_permlane32_swap((unsigned)x, (unsigned)x, false, false);
    return (int)(p.x | p.y);
}

// ---------------- kernel 0: convert weights fp32 -> bf16 into ws ----------------
__global__ __launch_bounds__(256) void convert_w_k(const float* __restrict__ W1,
                                                   const float* __restrict__ W2,
                                                   unsigned short* __restrict__ w1b,
                                                   unsigned short* __restrict__ w2b) {
    int i = blockIdx.x * 256 + threadIdx.x;  // 16384 threads, exact
    w1b[i] = f2bf(W1[i]);
    w2b[i] = f2bf(W2[i]);
}

// ================= fused kernel =================
// R12: W2 OFF the DS pipe. R11 (permlane diet, +3-5us) confirmed the
// DS direction but left all pipes ~half-idle; the remaining DS load is
// the 80 ds_read_b128/wave-tile of weights, and OccupancyPercent (~26%
// ~= 8 waves/CU, not the designed 16) suggests the two 66.5KB blocks may
// not co-reside (LDS alloc granularity). Both theories -> same fix:
//  - W2 fragments read DIRECTLY FROM GLOBAL (bf16 w2b in ws, 32KB,
//    L2-permanently-hot / mostly L1-resident; VMEM pipe, MFMA overlap
//    hides latency). DS ops/wave-tile 80 -> 48.
//  - LDS shrinks 66.5KB -> ~33.8KB (sW1 + sB1 only): block co-residency
//    guaranteed even under coarse LDS granularity -> 2-4 blocks/CU.
//  - Weights pre-converted to bf16 once (convert_w_k, ~2us) -> cheaper
//    sW1 staging too (uint4 copies, no cvt chain).
// Geometry: 512 threads, __launch_bounds__(512,2) (the only bound that
// never caused the 64-reg spill cap -- R3/R5 lessons).
//
// R7 recap (unchanged): GEMM1 swapped (mfma(wb,a)) so each lane holds H
// for its own sample; h-dimension globally permuted at staging (slot(h)
// = (2*(h>>5)+((h>>2)&1))*16 + ((h>>3)&3)*4 + (h&3) applied to W1 rows
// + b1; W2 read logical) so packed GEMM1 outputs concatenate into
// EXACTLY the K=32 GEMM2 A-frag; zero LDS H traffic, no __syncthreads
// in tile loop; b1 in MFMA C-init, b2 in oacc init.
// Solver: log-Newton base-2 (s += log2(v)*v/dv2), init = step from 0,
// permlane quad reductions, early break __all(|v-1|<1e-5); the -1 of F
// applies ONCE post-reduction. cvt_pk packs; next-tile x prefetch.
__global__ __launch_bounds__(512, 2) void fused_k(const float* __restrict__ x,
                                                  const float* __restrict__ r,
                                                  const unsigned short* __restrict__ w1b,
                                                  const float* __restrict__ b1,
                                                  const unsigned short* __restrict__ w2b,
                                                  const float* __restrict__ b2,
                                                  float* __restrict__ out,
                                                  int tiles_per_block) {
    __shared__ unsigned short sW1[256 * 64];  // 32 KB, PERMUTED rows, swizzled
    __shared__ float sB1[256];                //  1 KB, b1 at permuted slots

    int tid = threadIdx.x;

    // ---- stage W1 [256x64] bf16, row-PERMUTED by pi, swizzled
    const uint4* w1u = (const uint4*)w1b;
#pragma unroll
    for (int c = 0; c < 4; ++c) {
        int g = tid + c * 512;
        int h = g >> 3, ch = g & 7;  // logical row, 8-elem chunk
        int prow = ((h >> 5) * 2 + ((h >> 2) & 1)) * 16 + ((h >> 3) & 3) * 4 + (h & 3);
        *(uint4*)&sW1[prow * 64 + (ch ^ (prow & 7)) * 8] = w1u[g];
    }
    // ---- stage b1 at permuted slots
    if (tid < 256) {
        int h = tid;
        int prow = ((h >> 5) * 2 + ((h >> 2) & 1)) * 16 + ((h >> 3) & 3) * 4 + (h & 3);
        sB1[prow] = b1[h];
    }
    __syncthreads();

    int wave = tid >> 6, lane = tid & 63;
    int q = lane >> 4, l16 = lane & 15;
    int sx = l16 & 7;  // swizzle key for rows indexed by l16

    float bias2[4];
#pragma unroll
    for (int n = 0; n < 4; ++n) bias2[n] = b2[n * 16 + l16];

    // ---- per-thread rate chunks: coords {8q..8q+7} and {32+8q..+7}
    const float L2E2 = 2.8853900817779268f;  // 2*log2(e)
    float rl2[16];
    {
        const float4* r4 = (const float4*)r;
        float4 ra = r4[2 * q], rb = r4[2 * q + 1];
        float4 rc = r4[8 + 2 * q], rd = r4[8 + 2 * q + 1];
        rl2[0] = ra.x * L2E2; rl2[1] = ra.y * L2E2; rl2[2] = ra.z * L2E2; rl2[3] = ra.w * L2E2;
        rl2[4] = rb.x * L2E2; rl2[5] = rb.y * L2E2; rl2[6] = rb.z * L2E2; rl2[7] = rb.w * L2E2;
        rl2[8] = rc.x * L2E2; rl2[9] = rc.y * L2E2; rl2[10] = rc.z * L2E2; rl2[11] = rc.w * L2E2;
        rl2[12] = rd.x * L2E2; rl2[13] = rd.y * L2E2; rl2[14] = rd.z * L2E2; rl2[15] = rd.w * L2E2;
    }

    int myrow = wave * 16 + l16;  // 0..127
    size_t mb = (size_t)blockIdx.x * tiles_per_block * 128;
    const float4* xt = (const float4*)(x + (mb + myrow) * 64);  // tile 0, my row

    // ---- prefetch tile 0
    float4 va = xt[2 * q], vb = xt[2 * q + 1];
    float4 vc = xt[8 + 2 * q], vd = xt[8 + 2 * q + 1];

    for (int tt = 0; tt < tiles_per_block; ++tt) {
        size_t m0 = mb + (size_t)tt * 128;

        float xv[16];
        xv[0] = va.x; xv[1] = va.y; xv[2] = va.z; xv[3] = va.w;
        xv[4] = vb.x; xv[5] = vb.y; xv[6] = vb.z; xv[7] = vb.w;
        xv[8] = vc.x; xv[9] = vc.y; xv[10] = vc.z; xv[11] = vc.w;
        xv[12] = vd.x; xv[13] = vd.y; xv[14] = vd.z; xv[15] = vd.w;

        // ---- issue next tile's loads NOW (hide L3/HBM latency under solve+GEMM)
        {
            int nt = (tt + 1 < tiles_per_block) ? (tt + 1) : tt;
            const float4* xn = xt + (size_t)nt * 2048;  // 128 rows * 16 float4
            va = xn[2 * q]; vb = xn[2 * q + 1];
            vc = xn[8 + 2 * q]; vd = xn[8 + 2 * q + 1];
        }

        float x2[16], rx2[16];
        float sum0 = 0.f, sumr = 0.f;
        int nz = 0;
#pragma unroll
        for (int j = 0; j < 16; ++j) {
            x2[j] = xv[j] * xv[j];
            rx2[j] = rl2[j] * x2[j];
            sum0 += x2[j];
            sumr += rx2[j];
            nz |= (fabsf(xv[j]) > 1e-12f) ? 1 : 0;
        }
        // quad reduction (owners differ in lane bits 4,5) -- pure VALU
        sum0 = pl32_sum(pl16_sum(sum0));
        sumr = pl32_sum(pl16_sum(sumr));
        nz = pl32_or(pl16_or(nz));

        float s = 0.f;
        if (nz) {
            // init = log-Newton step from s=0
            s = __log2f(sum0) * sum0 * __builtin_amdgcn_rcpf(sumr);
#pragma unroll 1
            for (int it = 0; it < 10; ++it) {
                float ns = -s;
                float v = 0.f, dv = 0.f;
#pragma unroll
                for (int j = 0; j < 16; ++j) {
                    float e = __builtin_amdgcn_exp2f(ns * rl2[j]);
                    v = fmaf(e, x2[j], v);
                    dv = fmaf(e, rx2[j], dv);
                }
                v = pl32_sum(pl16_sum(v));
                dv = pl32_sum(pl16_sum(dv));
                if (__all(fabsf(v - 1.f) < 1e-5f)) break;
                // log-Newton in base 2: s += log2(v)*v/dv2
                s += __log2f(v) * v * __builtin_amdgcn_rcpf(dv);
            }
        }

        // ---- B-frags (GEMM1) from the solve: xs = x * 2^{-s*rl2/2}, packed
        float hs = -0.5f * s;
        unsigned pa[8];
#pragma unroll
        for (int j = 0; j < 8; ++j) {
            float ea = xv[2 * j] * __builtin_amdgcn_exp2f(hs * rl2[2 * j]);
            float eb = xv[2 * j + 1] * __builtin_amdgcn_exp2f(hs * rl2[2 * j + 1]);
            asm("v_cvt_pk_bf16_f32 %0, %1, %2" : "=v"(pa[j]) : "v"(ea), "v"(eb));
        }
        int4 w0 = make_int4((int)pa[0], (int)pa[1], (int)pa[2], (int)pa[3]);
        int4 w1 = make_int4((int)pa[4], (int)pa[5], (int)pa[6], (int)pa[7]);
        short8 a0 = *(short8*)&w0;
        short8 a1 = *(short8*)&w1;

        // e^s, fan out to the lanes that scale samples q*4+reg
        float es = __builtin_amdgcn_exp2f(s * 1.4426950408889634f);
        float sc[4];
#pragma unroll
        for (int reg = 0; reg < 4; ++reg) sc[reg] = __shfl(es, q * 4 + reg);

        floatx4 oacc[4];
#pragma unroll
        for (int n = 0; n < 4; ++n)
            oacc[n] = (floatx4){bias2[n], bias2[n], bias2[n], bias2[n]};

#pragma unroll
        for (int hc = 0; hc < 8; ++hc) {
            // ---- GEMM1 (swapped), subtile pair (2hc, 2hc+1):
            // acc[reg] = H[logical h = hc*32 + q*8 + p*4 + reg][sample l16]
            unsigned pk0, pk1, pk2, pk3;
            {
                int t = hc * 2;
                int row = t * 16 + l16;
                short8 wb0 = *(const short8*)&sW1[row * 64 + (q ^ sx) * 8];
                short8 wb1 = *(const short8*)&sW1[row * 64 + ((q + 4) ^ sx) * 8];
                const float4 bb = *(const float4*)&sB1[t * 16 + q * 4];
                floatx4 acc = (floatx4){bb.x, bb.y, bb.z, bb.w};
                acc = __builtin_amdgcn_mfma_f32_16x16x32_bf16(wb0, a0, acc, 0, 0, 0);
                acc = __builtin_amdgcn_mfma_f32_16x16x32_bf16(wb1, a1, acc, 0, 0, 0);
                float h0 = fmaxf(acc[0], 0.f), h1 = fmaxf(acc[1], 0.f);
                float h2 = fmaxf(acc[2], 0.f), h3 = fmaxf(acc[3], 0.f);
                asm("v_cvt_pk_bf16_f32 %0, %1, %2" : "=v"(pk0) : "v"(h0), "v"(h1));
                asm("v_cvt_pk_bf16_f32 %0, %1, %2" : "=v"(pk1) : "v"(h2), "v"(h3));
            }
            {
                int t = hc * 2 + 1;
                int row = t * 16 + l16;
                short8 wb0 = *(const short8*)&sW1[row * 64 + (q ^ sx) * 8];
                short8 wb1 = *(const short8*)&sW1[row * 64 + ((q + 4) ^ sx) * 8];
                const float4 bb = *(const float4*)&sB1[t * 16 + q * 4];
                floatx4 acc = (floatx4){bb.x, bb.y, bb.z, bb.w};
                acc = __builtin_amdgcn_mfma_f32_16x16x32_bf16(wb0, a0, acc, 0, 0, 0);
                acc = __builtin_amdgcn_mfma_f32_16x16x32_bf16(wb1, a1, acc, 0, 0, 0);
                float h0 = fmaxf(acc[0], 0.f), h1 = fmaxf(acc[1], 0.f);
                float h2 = fmaxf(acc[2], 0.f), h3 = fmaxf(acc[3], 0.f);
                asm("v_cvt_pk_bf16_f32 %0, %1, %2" : "=v"(pk2) : "v"(h0), "v"(h1));
                asm("v_cvt_pk_bf16_f32 %0, %1, %2" : "=v"(pk3) : "v"(h2), "v"(h3));
            }
            // ---- A-frag for GEMM2 K-chunk hc: ha[j] = H[sample l16][hc*32+q*8+j]
            int4 hw = make_int4((int)pk0, (int)pk1, (int)pk2, (int)pk3);
            short8 ha = *(short8*)&hw;
            // ---- GEMM2: W2 fragments straight from GLOBAL (L1/L2-hot bf16;
            // VMEM pipe, MFMA hides latency). No swizzle needed.
#pragma unroll
            for (int n = 0; n < 4; ++n) {
                int orow = n * 16 + l16;  // W2 row = o index
                short8 wb = *(const short8*)(w2b + orow * 256 + (hc * 4 + q) * 8);
                oacc[n] = __builtin_amdgcn_mfma_f32_16x16x32_bf16(ha, wb, oacc[n], 0, 0, 0);
            }
        }
        // ---- epilogue: out = (H @ W2^T + b2) * e^s   (b2 folded into init)
#pragma unroll
        for (int n = 0; n < 4; ++n) {
#pragma unroll
            for (int reg = 0; reg < 4; ++reg) {
                out[(m0 + wave * 16 + q * 4 + reg) * 64 + n * 16 + l16] =
                    oacc[n][reg] * sc[reg];
            }
        }
    }
}

extern "C" void kernel_launch(void* const* d_in, const int* in_sizes, int n_in,
                              void* d_out, int out_size, void* d_ws, size_t ws_size,
                              hipStream_t stream) {
    const float* x  = (const float*)d_in[0];
    const float* r  = (const float*)d_in[1];
    const float* W1 = (const float*)d_in[2];
    const float* b1 = (const float*)d_in[3];
    const float* W2 = (const float*)d_in[4];
    const float* b2 = (const float*)d_in[5];
    float* out = (float*)d_out;
    int B = in_sizes[0] / 64;  // 262144

    char* ws = (char*)d_ws;
    unsigned short* w1b = (unsigned short*)ws;            // 32768 B
    unsigned short* w2b = (unsigned short*)(ws + 32768);  // 32768 B

    convert_w_k<<<64, 256, 0, stream>>>(W1, W2, w1b, w2b);

    int tiles = B / 128;           // 2048 tiles of 128 samples
    int blocks = 512;
    int tpb = tiles / blocks;      // 4

    fused_k<<<blocks, 512, 0, stream>>>(x, r, w1b, b1, w2b, b2, out, tpb);
}